// Round 9
// baseline (387.658 us; speedup 1.0000x reference)
//
#include <hip/hip_runtime.h>
#include <math.h>

#define CHI 64
#define CHO 64
#define HH 128
#define WW 128
#define NB 4
#define KK 9
#define NOFF 27
#define NOFFP 28              // padded for float2 packing
#define EPSV 1e-5f
#define PLANE (HH * WW)

typedef float v2f __attribute__((ext_vector_type(2)));
typedef float f2v __attribute__((ext_vector_type(2), aligned(4)));
typedef float f32x4 __attribute__((ext_vector_type(4)));
typedef short bf16x8 __attribute__((ext_vector_type(8)));

__device__ __forceinline__ v2f pkfma(v2f a, v2f b, v2f c) {
#if __has_builtin(__builtin_elementwise_fma)
    return __builtin_elementwise_fma(a, b, c);
#else
    return a * b + c;
#endif
}

// fp32 -> bf16 round-to-nearest-even
__device__ __forceinline__ unsigned short f2bf(float f) {
    unsigned u = __float_as_uint(f);
    u += 0x7fff + ((u >> 16) & 1);
    return (unsigned short)(u >> 16);
}

// bilinear coeffs + row offsets for tap kk (column-pair trick folded in)
__device__ __forceinline__ void mkcoef(int kk, int h, int w, float dy, float dx, float mo,
                                       const float* __restrict__ b_off,
                                       v2f& cA, v2f& cB, unsigned& o0, unsigned& o1) {
    dy += b_off[2 * kk];
    dx += b_off[2 * kk + 1];
    mo += b_off[18 + kk];
    float m  = 1.f / (1.f + __expf(-mo));
    int ky = kk / 3, kx = kk - ky * 3;
    float py  = (float)(h - 1 + ky) + dy;
    float px_ = (float)(w - 1 + kx) + dx;
    float fy0 = floorf(py), fx0 = floorf(px_);
    float wy = py - fy0, wx = px_ - fx0;
    int y0 = (int)fy0, x0 = (int)fx0;
    int y1 = y0 + 1, x1 = x0 + 1;
    bool vy0 = (unsigned)y0 < HH, vy1 = (unsigned)y1 < HH;
    bool vx0 = (unsigned)x0 < WW, vx1 = (unsigned)x1 < WW;
    float a00 = (vy0 && vx0) ? (1.f - wy) * (1.f - wx) * m : 0.f;
    float a01 = (vy0 && vx1) ? (1.f - wy) * wx * m : 0.f;
    float a10 = (vy1 && vx0) ? wy * (1.f - wx) * m : 0.f;
    float a11 = (vy1 && vx1) ? wy * wx * m : 0.f;
    int xbc = min(max(x0, 0), WW - 2);
    bool sel = (x0 == xbc);
    cA = (v2f){ sel ? a00 : a01, sel ? a01 : a00 };
    cB = (v2f){ sel ? a10 : a11, sel ? a11 : a10 };
    int cy0 = min(max(y0, 0), HH - 1), cy1 = min(max(y1, 0), HH - 1);
    o0 = (unsigned)(cy0 * WW + xbc);
    o1 = (unsigned)(cy1 * WW + xbc);
}

// ---------------- prep ----------------
// w_bf: A-fragment table for mfma_f32_16x16x32_bf16.
//   flat idx = (((kk*4 + ct)*2 + ks)*64 + lane)*8 + j
//   holds A[m][k]: co = ct*16 + (lane&15), ci = ks*32 + ((lane>>4)&3)*8 + j
// wo_t[ci][tap][c28] = w_off[c][ci][tap]  (fp32, for offset conv)
__global__ __launch_bounds__(256) void prep_kernel(const float* __restrict__ w,
                                                   const float* __restrict__ w_off,
                                                   unsigned short* __restrict__ w_bf,
                                                   float* __restrict__ wo_t) {
    int i = blockIdx.x * 256 + threadIdx.x;    // grid 144*256 = 36864 exactly
    {
        int j    = i & 7;
        int lane = (i >> 3) & 63;
        int ks   = (i >> 9) & 1;
        int ct   = (i >> 10) & 3;
        int kk   = i >> 12;                    // 0..8
        int co   = ct * 16 + (lane & 15);
        int ci   = ks * 32 + ((lane >> 4) & 3) * 8 + j;
        w_bf[i]  = f2bf(w[(co * CHI + ci) * KK + kk]);
    }
    if (i < CHI * KK * NOFFP) {
        int ci  = i / (KK * NOFFP);
        int r   = i % (KK * NOFFP);
        int tap = r / NOFFP;
        int c   = r % NOFFP;
        wo_t[i] = (c < NOFF) ? w_off[(c * CHI + ci) * KK + tap] : 0.f;
    }
}

// ---------------- offset conv ----------------
// 512 threads: w = tid&127, chunk = tid>>7 (4 chunks x 16 ci, SGPR-forced).
// Weights staged in LDS (63 KB) -> ds_read_b128 broadcast, NO s_load chain,
// no K$ thrash. smem reused as the combine buffer after the main loop.
// grid 512: blockIdx%8 -> (b, h-half) for XCD L2 locality.
__global__ __launch_bounds__(512) void off_conv_kernel(const float* __restrict__ x,
                                                       const float* __restrict__ wo_t,
                                                       float* __restrict__ off) {
    const int id    = blockIdx.x;
    const int slot  = id & 7;
    const int b     = slot & 3;
    const int h     = (slot >> 2) * 64 + (id >> 3);
    const int w     = threadIdx.x & 127;
    const int chunk = __builtin_amdgcn_readfirstlane(threadIdx.x >> 7);

    __shared__ __align__(16) float smem[CHI * KK * NOFFP];   // 64512 B
    for (int i = threadIdx.x; i < CHI * KK * NOFFP / 4; i += 512)
        ((float4*)smem)[i] = ((const float4*)wo_t)[i];
    __syncthreads();

    v2f acc[NOFFP / 2];
#pragma unroll
    for (int c = 0; c < NOFFP / 2; c++) acc[c] = (v2f)(0.f);

    const float* xb  = x + ((size_t)b * CHI + chunk * 16) * PLANE;
    const float* wls = smem + chunk * 16 * KK * NOFFP;

    float xv[KK], nxv[KK];
#pragma unroll
    for (int ky = 0; ky < 3; ky++) {
        int hr = h - 1 + ky;
        bool rok = (unsigned)hr < HH;
#pragma unroll
        for (int kx = 0; kx < 3; kx++) {
            int wc = w - 1 + kx;
            xv[ky * 3 + kx] = (rok && (unsigned)wc < WW) ? xb[hr * WW + wc] : 0.f;
        }
    }

#pragma unroll 2
    for (int ci = 0; ci < 16; ci++) {
        if (ci < 15) {
            const float* nplane = xb + (ci + 1) * PLANE;
#pragma unroll
            for (int ky = 0; ky < 3; ky++) {
                int hr = h - 1 + ky;
                bool rok = (unsigned)hr < HH;
#pragma unroll
                for (int kx = 0; kx < 3; kx++) {
                    int wc = w - 1 + kx;
                    nxv[ky * 3 + kx] = (rok && (unsigned)wc < WW) ? nplane[hr * WW + wc] : 0.f;
                }
            }
        }
#pragma unroll
        for (int t = 0; t < KK; t++) {
            v2f xv2 = {xv[t], xv[t]};
            const f32x4* wp = (const f32x4*)(wls + (ci * KK + t) * NOFFP);
#pragma unroll
            for (int c = 0; c < 7; c++) {
                f32x4 ww = wp[c];                  // ds_read_b128 broadcast
                v2f w01 = {ww[0], ww[1]};
                v2f w23 = {ww[2], ww[3]};
                acc[2 * c]     = pkfma(xv2, w01, acc[2 * c]);
                acc[2 * c + 1] = pkfma(xv2, w23, acc[2 * c + 1]);
            }
        }
#pragma unroll
        for (int t = 0; t < KK; t++) xv[t] = nxv[t];
    }

    __syncthreads();   // all weight reads done -> reuse smem as combine buffer
    v2f (*lacc)[128][NOFFP / 2] = (v2f(*)[128][NOFFP / 2])smem;   // 43008 B
    if (chunk > 0) {
#pragma unroll
        for (int c = 0; c < NOFFP / 2; c++) lacc[chunk - 1][w][c] = acc[c];
    }
    __syncthreads();
    if (chunk == 0) {
#pragma unroll
        for (int c = 0; c < NOFFP / 2; c++)
            acc[c] = acc[c] + lacc[0][w][c] + lacc[1][w][c] + lacc[2][w][c];
        float* accs = (float*)acc;
#pragma unroll
        for (int c = 0; c < NOFF; c++)
            off[(((size_t)b * NOFF + c) * HH + h) * WW + w] = accs[c];
    }
}

// ---------------- deform sample + MFMA main conv (pipelined) ----------------
// Block 256 threads = 4 waves, 64 px (half row) x all 64 co.
// Pipeline per kk: [A-loads + raw-offset prefetch] [convert prev gathers ->
// LDS buf] [barrier] [issue kk+1 gathers -> regs, in flight] [MFMA buf].
// Double LDS buffer + ONE barrier per kk. A-fragments loaded BEFORE gathers
// so their vmcnt wait doesn't drain the gather queue.
// grid 1024: blockIdx%8 -> (b, h-half) for XCD L2 locality.
__global__ __launch_bounds__(256, 4) void deform_kernel(const float* __restrict__ x,
                                                        const unsigned short* __restrict__ w_bf,
                                                        const float* __restrict__ off,
                                                        const float* __restrict__ b_off,
                                                        const float* __restrict__ bias,
                                                        float* __restrict__ out) {
    const int id    = blockIdx.x;
    const int slot  = id & 7;
    const int b     = slot >> 1;
    const int rb    = id >> 3;                 // 0..127
    const int h     = (slot & 1) * 64 + (rb >> 1);
    const int whalf = rb & 1;
    const int tid   = threadIdx.x;
    const int lane  = tid & 63;

    // producer roles
    const int pxs      = tid & 63;
    const int cig      = __builtin_amdgcn_readfirstlane(tid >> 6); // 16-ci group
    const int pxin_s   = pxs & 15, pxtile_s = pxs >> 4;
    const int ks       = cig >> 1;             // K-step
    const int qb       = (cig & 1) << 1;       // quad base
    // consumer roles
    const int wave  = cig;                     // co-tile
    const int quadc = lane >> 4, pxinc = lane & 15;
    const int colc  = pxinc ^ quadc;           // XOR bank swizzle

    __shared__ __align__(16) unsigned short vbuf[2][4096];  // 2 x 8 KB

    f32x4 acc[4];
#pragma unroll
    for (int t = 0; t < 4; t++) acc[t] = (f32x4){0.f, 0.f, 0.f, 0.f};

    const float* xb   = x + ((size_t)b * CHI + cig * 16) * PLANE;
    const float* offb = off + (size_t)b * NOFF * PLANE + h * WW + whalf * 64 + pxs;
    const int w = whalf * 64 + pxs;

    f2v q0[16], q1[16];
    v2f cAh, cBh;
    unsigned o0, o1;

    // prologue: kk=0 coeffs + gathers
    {
        float rdy = offb[0];
        float rdx = offb[PLANE];
        float rmo = offb[18 * PLANE];
        mkcoef(0, h, w, rdy, rdx, rmo, b_off, cAh, cBh, o0, o1);
        const float* pl = xb;
#pragma unroll
        for (int ci = 0; ci < 16; ci++) {
            q0[ci] = *(const f2v*)(pl + o0);
            q1[ci] = *(const f2v*)(pl + o1);
            pl += PLANE;
        }
    }

    int buf = 0;
#pragma unroll 1
    for (int kk = 0; kk < KK; kk++) {
        // A-fragments for THIS kk — issued first so vmcnt wait excludes gathers
        const bf16x8* wb = (const bf16x8*)w_bf + (size_t)((kk * 4 + wave) * 2) * 64;
        bf16x8 A0 = wb[lane];
        bf16x8 A1 = wb[64 + lane];
        // raw offsets for kk+1 (latency hidden under convert+store+barrier)
        float ndy = 0.f, ndx = 0.f, nmo = 0.f;
        if (kk < 8) {
            ndy = offb[(2 * kk + 2) * PLANE];
            ndx = offb[(2 * kk + 3) * PLANE];
            nmo = offb[(19 + kk) * PLANE];
        }

        // convert prev-issued gathers -> bf16 -> LDS fragments
        bf16x8* vals = (bf16x8*)vbuf[buf];
#pragma unroll
        for (int gg = 0; gg < 2; gg++) {
            bf16x8 tmp;
#pragma unroll
            for (int j = 0; j < 8; j++) {
                v2f t = pkfma((v2f)q1[gg * 8 + j], cBh, (v2f)q0[gg * 8 + j] * cAh);
                tmp[j] = (short)f2bf(t.x + t.y);
            }
            int quad = qb | gg;
            vals[(pxtile_s * 2 + ks) * 64 + (quad << 4) + (pxin_s ^ quad)] = tmp;
        }
        __syncthreads();

        // issue next kk's gathers — stay in flight across MFMA
        if (kk < 8) {
            mkcoef(kk + 1, h, w, ndy, ndx, nmo, b_off, cAh, cBh, o0, o1);
            const float* pl = xb;
#pragma unroll
            for (int ci = 0; ci < 16; ci++) {
                q0[ci] = *(const f2v*)(pl + o0);
                q1[ci] = *(const f2v*)(pl + o1);
                pl += PLANE;
            }
        }

        // MFMA: 16 co x 4 px-tiles, K=64 over 2 steps
#pragma unroll
        for (int t = 0; t < 4; t++) {
            bf16x8 B0 = vals[(t * 2 + 0) * 64 + (quadc << 4) + colc];
            bf16x8 B1 = vals[(t * 2 + 1) * 64 + (quadc << 4) + colc];
            acc[t] = __builtin_amdgcn_mfma_f32_16x16x32_bf16(A0, B0, acc[t], 0, 0, 0);
            acc[t] = __builtin_amdgcn_mfma_f32_16x16x32_bf16(A1, B1, acc[t], 0, 0, 0);
        }
        buf ^= 1;
        // no second barrier needed: next store targets the OTHER buffer, whose
        // last readers finished before the barrier above (waitcnt at barrier)
    }

    // epilogue: C/D layout col(n=px)=lane&15, row(m=co)=(lane>>4)*4+reg
    float bi[4];
#pragma unroll
    for (int r = 0; r < 4; r++) bi[r] = bias[wave * 16 + quadc * 4 + r];
#pragma unroll
    for (int t = 0; t < 4; t++) {
#pragma unroll
        for (int r = 0; r < 4; r++) {
            int co = wave * 16 + quadc * 4 + r;
            out[(((size_t)b * CHO + co) * HH + h) * WW + whalf * 64 + t * 16 + pxinc] =
                acc[t][r] + bi[r];
        }
    }
}

// ---------------- per-channel stats (sum, sumsq) ----------------
__global__ __launch_bounds__(256) void stats_kernel(const float* __restrict__ y,
                                                    float* __restrict__ stats) {
    const int co = blockIdx.x;
    const int b  = blockIdx.y;
    const float4* p4 = (const float4*)(y + ((size_t)b * CHO + co) * PLANE);
    float s = 0.f, s2 = 0.f;
    for (int i = threadIdx.x; i < PLANE / 4; i += 256) {
        float4 v = p4[i];
        s  += v.x + v.y + v.z + v.w;
        s2 += v.x * v.x + v.y * v.y + v.z * v.z + v.w * v.w;
    }
#pragma unroll
    for (int o = 32; o > 0; o >>= 1) {
        s  += __shfl_down(s, o, 64);
        s2 += __shfl_down(s2, o, 64);
    }
    __shared__ float ls[4], ls2[4];
    int lane = threadIdx.x & 63, wv = threadIdx.x >> 6;
    if (lane == 0) { ls[wv] = s; ls2[wv] = s2; }
    __syncthreads();
    if (threadIdx.x == 0) {
        float ts = 0.f, t2 = 0.f;
#pragma unroll
        for (int i = 0; i < 4; i++) { ts += ls[i]; t2 += ls2[i]; }
        atomicAdd(&stats[co], ts);
        atomicAdd(&stats[64 + co], t2);
    }
}

// ---------------- BN + ReLU, in place on d_out ----------------
__global__ __launch_bounds__(256) void bn_kernel(float* __restrict__ y,
                                                 const float* __restrict__ stats,
                                                 const float* __restrict__ gamma,
                                                 const float* __restrict__ beta) {
    size_t base = (size_t)blockIdx.x * 1024;
    int co = (int)((base >> 14) & 63);
    const float inv_n = 1.f / 65536.f;
    float mean = stats[co] * inv_n;
    float var  = stats[64 + co] * inv_n - mean * mean;
    float sc = gamma[co] * rsqrtf(var + EPSV);
    float sh = beta[co] - mean * sc;
    float4* p = (float4*)(y + base);
    float4 v = p[threadIdx.x];
    v.x = fmaxf(fmaf(v.x, sc, sh), 0.f);
    v.y = fmaxf(fmaf(v.y, sc, sh), 0.f);
    v.z = fmaxf(fmaf(v.z, sc, sh), 0.f);
    v.w = fmaxf(fmaf(v.w, sc, sh), 0.f);
    p[threadIdx.x] = v;
}

extern "C" void kernel_launch(void* const* d_in, const int* in_sizes, int n_in,
                              void* d_out, int out_size, void* d_ws, size_t ws_size,
                              hipStream_t stream) {
    const float* x     = (const float*)d_in[0];
    const float* w_off = (const float*)d_in[1];
    const float* b_off = (const float*)d_in[2];
    const float* wmat  = (const float*)d_in[3];
    const float* bvec  = (const float*)d_in[4];
    const float* gamma = (const float*)d_in[5];
    const float* beta  = (const float*)d_in[6];
    float* out = (float*)d_out;

    char* ws = (char*)d_ws;
    float* stats          = (float*)ws;                  // 512 B
    unsigned short* w_bf  = (unsigned short*)(ws + 1024);// 73728 B
    float* wo_t           = (float*)(ws + 74752);        // 64512 B (16B aligned)
    float* off            = (float*)(ws + 139264);       // 7077888 B

    hipMemsetAsync(stats, 0, 512, stream);
    prep_kernel<<<144, 256, 0, stream>>>(wmat, w_off, w_bf, wo_t);
    off_conv_kernel<<<512, 512, 0, stream>>>(x, wo_t, off);
    deform_kernel<<<1024, 256, 0, stream>>>(x, w_bf, off, b_off, bvec, out);
    stats_kernel<<<dim3(CHO, NB), 256, 0, stream>>>(out, stats);
    bn_kernel<<<4096, 256, 0, stream>>>(out, stats, gamma, beta);
}

// Round 10
// 193.396 us; speedup vs baseline: 2.0045x; 2.0045x over previous
//
#include <hip/hip_runtime.h>
#include <math.h>

#define CHI 64
#define CHO 64
#define HH 128
#define WW 128
#define NB 4
#define KK 9
#define NOFF 27
#define EPSV 1e-5f
#define PLANE (HH * WW)
#define SP 72                 // LDS ci-stride (bytes=144: 16B-aligned, uniform banks)

typedef float v2f __attribute__((ext_vector_type(2)));
typedef float f2v __attribute__((ext_vector_type(2), aligned(4)));
typedef float f32x4 __attribute__((ext_vector_type(4)));
typedef short bf16x8 __attribute__((ext_vector_type(8)));

__device__ __forceinline__ v2f pkfma(v2f a, v2f b, v2f c) {
#if __has_builtin(__builtin_elementwise_fma)
    return __builtin_elementwise_fma(a, b, c);
#else
    return a * b + c;
#endif
}

// fp32 -> bf16 round-to-nearest-even
__device__ __forceinline__ unsigned short f2bf(float f) {
    unsigned u = __float_as_uint(f);
    u += 0x7fff + ((u >> 16) & 1);
    return (unsigned short)(u >> 16);
}

// ---------------- prep: pack MFMA A-fragment tables (bf16) ----------------
// A-frag layout (mfma_f32_16x16x32_bf16): lane holds A[m=lane&15][k=(lane>>4)*8+j]
// w_bf  (deform):  elem = (((kk*4+ct)*2+ks)*64 + lane)*8 + j ; co=ct*16+m, ci=ks*32+k
// woA (off_conv):  elem = (((kk*2+ks)*2+ct)*64 + lane)*8 + j ; c =ct*16+m (0 if >=27)
__global__ __launch_bounds__(256) void prep_kernel(const float* __restrict__ w,
                                                   const float* __restrict__ w_off,
                                                   unsigned short* __restrict__ w_bf,
                                                   unsigned short* __restrict__ woA) {
    int i = blockIdx.x * 256 + threadIdx.x;    // grid 144*256 = 36864 exactly
    {
        int j    = i & 7;
        int lane = (i >> 3) & 63;
        int ks   = (i >> 9) & 1;
        int ct   = (i >> 10) & 3;
        int kk   = i >> 12;                    // 0..8
        int co   = ct * 16 + (lane & 15);
        int ci   = ks * 32 + ((lane >> 4) & 3) * 8 + j;
        w_bf[i]  = f2bf(w[(co * CHI + ci) * KK + kk]);
    }
    if (i < 18432) {
        int j    = i & 7;
        int lane = (i >> 3) & 63;
        int ct   = (i >> 9) & 1;
        int ks   = (i >> 10) & 1;
        int kk   = i >> 11;                    // 0..8
        int c    = ct * 16 + (lane & 15);
        int ci   = ks * 32 + (lane >> 4) * 8 + j;
        woA[i]   = (c < NOFF) ? f2bf(w_off[(c * CHI + ci) * KK + kk]) : (unsigned short)0;
    }
}

// ---------------- offset conv via MFMA ----------------
// Block 256 = 4 waves, half-row (64 px) x all 27 co. Stage x window
// (3 rows x 66 px x 64 ci) as bf16 in LDS, then 9 taps x K=64 MFMA.
// Weights come as prepacked per-lane A-fragments (vector loads, L2-hot)
// — NO scalar-load chain (R6-R8 disease), NO uniform-data-in-LDS (R9 disease).
// grid 1024: blockIdx%8 -> (b, h-half) XCD swizzle, matching deform.
__global__ __launch_bounds__(256) void off_conv_kernel(const float* __restrict__ x,
                                                       const unsigned short* __restrict__ woA,
                                                       float* __restrict__ off) {
    const int id    = blockIdx.x;
    const int slot  = id & 7;
    const int b     = slot >> 1;
    const int rb    = id >> 3;                 // 0..127
    const int h     = (slot & 1) * 64 + (rb >> 1);
    const int whalf = rb & 1;
    const int w0    = whalf * 64;
    const int tid   = threadIdx.x;
    const int lane  = tid & 63;
    const int px    = tid & 63;
    const int wv    = __builtin_amdgcn_readfirstlane(tid >> 6);  // wave id

    __shared__ __align__(16) unsigned short xs[3 * 66 * SP];     // 28512 B

    // stage: 192 (ky,ci) pairs, one pair per wave-iteration, px = lane
    for (int it = 0; it < 48; it++) {
        int pair = it * 4 + wv;
        int ky = pair >> 6;                    // 0..2
        int ci = pair & 63;
        int hr = h - 1 + ky;
        bool rok = (unsigned)hr < HH;
        const float* base = x + (((size_t)b * CHI + ci) * HH + (rok ? hr : 0)) * WW;
        float v = rok ? base[w0 + px] : 0.f;   // pxpos = px+1  (wc = w0+px)
        xs[(ky * 66 + px + 1) * SP + ci] = f2bf(v);
        if (px < 2) {                          // halo: pxpos 0 and 65
            int p  = px * 65;
            int wc = w0 - 1 + p;
            float hv = (rok && (unsigned)wc < WW) ? base[wc] : 0.f;
            xs[(ky * 66 + p) * SP + ci] = f2bf(hv);
        }
    }
    __syncthreads();

    const int quad = lane >> 4, pxin = lane & 15;   // B: k=quad*8+j, n=pxin
    f32x4 acc0 = {0.f, 0.f, 0.f, 0.f};             // co 0..15
    f32x4 acc1 = {0.f, 0.f, 0.f, 0.f};             // co 16..26 (+pad)

#pragma unroll 1
    for (int kk = 0; kk < KK; kk++) {
        const int ky = kk / 3, kx = kk - ky * 3;
#pragma unroll
        for (int ks = 0; ks < 2; ks++) {
            const bf16x8* wa = (const bf16x8*)woA + (size_t)((kk * 2 + ks) * 2) * 64;
            bf16x8 A0 = wa[lane];
            bf16x8 A1 = wa[64 + lane];
            bf16x8 B = *(const bf16x8*)&xs[(ky * 66 + wv * 16 + pxin + kx) * SP
                                           + ks * 32 + quad * 8];
            acc0 = __builtin_amdgcn_mfma_f32_16x16x32_bf16(A0, B, acc0, 0, 0, 0);
            acc1 = __builtin_amdgcn_mfma_f32_16x16x32_bf16(A1, B, acc1, 0, 0, 0);
        }
    }

    // C layout: col(n=px)=lane&15, row(m=c)=(lane>>4)*4+reg
    float* outp = off + ((size_t)b * NOFF * HH + h) * WW + w0 + wv * 16 + pxin;
#pragma unroll
    for (int r = 0; r < 4; r++) {
        int c0 = quad * 4 + r;
        outp[c0 * PLANE] = acc0[r];
        int c1 = 16 + quad * 4 + r;
        if (c1 < NOFF) outp[c1 * PLANE] = acc1[r];
    }
}

// ---------------- deform sample + MFMA main conv (R8 proven, 74 us) --------
__global__ __launch_bounds__(256, 2) void deform_kernel(const float* __restrict__ x,
                                                        const unsigned short* __restrict__ w_bf,
                                                        const float* __restrict__ off,
                                                        const float* __restrict__ b_off,
                                                        const float* __restrict__ bias,
                                                        float* __restrict__ out) {
    const int id    = blockIdx.x;
    const int slot  = id & 7;
    const int b     = slot >> 1;
    const int rb    = id >> 3;                 // 0..127
    const int h     = (slot & 1) * 64 + (rb >> 1);
    const int whalf = rb & 1;
    const int tid   = threadIdx.x;
    const int lane  = tid & 63;

    const int pxs      = tid & 63;
    const int cig      = __builtin_amdgcn_readfirstlane(tid >> 6);
    const int pxin_s   = pxs & 15, pxtile_s = pxs >> 4;
    const int wave  = cig;
    const int quadc = lane >> 4, pxinc = lane & 15;
    const int colc  = pxinc ^ quadc;

    __shared__ __align__(16) unsigned short vbuf[4096];
    bf16x8* vals = (bf16x8*)vbuf;

    f32x4 acc[4];
#pragma unroll
    for (int t = 0; t < 4; t++) acc[t] = (f32x4){0.f, 0.f, 0.f, 0.f};

    const float* xb   = x + ((size_t)b * CHI + cig * 16) * PLANE;
    const float* offb = off + (size_t)b * NOFF * PLANE + h * WW + whalf * 64 + pxs;
    const int w = whalf * 64 + pxs;

#pragma unroll 1
    for (int kk = 0; kk < KK; kk++) {
        const int ky = kk / 3, kx = kk % 3;
        float dy = offb[(2 * kk) * PLANE]     + b_off[2 * kk];
        float dx = offb[(2 * kk + 1) * PLANE] + b_off[2 * kk + 1];
        float mo = offb[(18 + kk) * PLANE]    + b_off[18 + kk];
        float m  = 1.f / (1.f + __expf(-mo));

        float py = (float)(h - 1 + ky) + dy;
        float px_ = (float)(w - 1 + kx) + dx;
        float fy0 = floorf(py), fx0 = floorf(px_);
        float wy = py - fy0, wx = px_ - fx0;
        int y0 = (int)fy0, x0 = (int)fx0;
        int y1 = y0 + 1, x1 = x0 + 1;
        bool vy0 = (unsigned)y0 < HH, vy1 = (unsigned)y1 < HH;
        bool vx0 = (unsigned)x0 < WW, vx1 = (unsigned)x1 < WW;
        float a00 = (vy0 && vx0) ? (1.f - wy) * (1.f - wx) * m : 0.f;
        float a01 = (vy0 && vx1) ? (1.f - wy) * wx * m : 0.f;
        float a10 = (vy1 && vx0) ? wy * (1.f - wx) * m : 0.f;
        float a11 = (vy1 && vx1) ? wy * wx * m : 0.f;

        int xbc = min(max(x0, 0), WW - 2);
        bool sel = (x0 == xbc);
        v2f cA = { sel ? a00 : a01, sel ? a01 : a00 };
        v2f cB = { sel ? a10 : a11, sel ? a11 : a10 };
        int cy0 = min(max(y0, 0), HH - 1), cy1 = min(max(y1, 0), HH - 1);
        const unsigned o0 = (unsigned)(cy0 * WW + xbc);
        const unsigned o1 = (unsigned)(cy1 * WW + xbc);

        const float* pl = xb;
#pragma unroll
        for (int gg = 0; gg < 2; gg++) {
            bf16x8 tmp;
#pragma unroll
            for (int j = 0; j < 8; j++) {
                f2v p0 = *(const f2v*)(pl + o0);
                f2v p1 = *(const f2v*)(pl + o1);
                v2f t = pkfma((v2f)p1, cB, (v2f)p0 * cA);
                tmp[j] = (short)f2bf(t.x + t.y);
                pl += PLANE;
            }
            int quad = ((cig & 1) << 1) | gg;
            int ks   = cig >> 1;
            vals[(pxtile_s * 2 + ks) * 64 + (quad << 4) + (pxin_s ^ quad)] = tmp;
        }
        __syncthreads();

        const bf16x8* wb = (const bf16x8*)w_bf + (size_t)((kk * 4 + wave) * 2) * 64;
        bf16x8 A0 = wb[lane];
        bf16x8 A1 = wb[64 + lane];
#pragma unroll
        for (int t = 0; t < 4; t++) {
            bf16x8 B0 = vals[(t * 2 + 0) * 64 + (quadc << 4) + colc];
            bf16x8 B1 = vals[(t * 2 + 1) * 64 + (quadc << 4) + colc];
            acc[t] = __builtin_amdgcn_mfma_f32_16x16x32_bf16(A0, B0, acc[t], 0, 0, 0);
            acc[t] = __builtin_amdgcn_mfma_f32_16x16x32_bf16(A1, B1, acc[t], 0, 0, 0);
        }
        __syncthreads();
    }

    float bi[4];
#pragma unroll
    for (int r = 0; r < 4; r++) bi[r] = bias[wave * 16 + quadc * 4 + r];
#pragma unroll
    for (int t = 0; t < 4; t++) {
#pragma unroll
        for (int r = 0; r < 4; r++) {
            int co = wave * 16 + quadc * 4 + r;
            out[(((size_t)b * CHO + co) * HH + h) * WW + whalf * 64 + t * 16 + pxinc] =
                acc[t][r] + bi[r];
        }
    }
}

// ---------------- per-channel stats (sum, sumsq) ----------------
__global__ __launch_bounds__(256) void stats_kernel(const float* __restrict__ y,
                                                    float* __restrict__ stats) {
    const int co = blockIdx.x;
    const int b  = blockIdx.y;
    const float4* p4 = (const float4*)(y + ((size_t)b * CHO + co) * PLANE);
    float s = 0.f, s2 = 0.f;
    for (int i = threadIdx.x; i < PLANE / 4; i += 256) {
        float4 v = p4[i];
        s  += v.x + v.y + v.z + v.w;
        s2 += v.x * v.x + v.y * v.y + v.z * v.z + v.w * v.w;
    }
#pragma unroll
    for (int o = 32; o > 0; o >>= 1) {
        s  += __shfl_down(s, o, 64);
        s2 += __shfl_down(s2, o, 64);
    }
    __shared__ float ls[4], ls2[4];
    int lane = threadIdx.x & 63, wvv = threadIdx.x >> 6;
    if (lane == 0) { ls[wvv] = s; ls2[wvv] = s2; }
    __syncthreads();
    if (threadIdx.x == 0) {
        float ts = 0.f, t2 = 0.f;
#pragma unroll
        for (int i = 0; i < 4; i++) { ts += ls[i]; t2 += ls2[i]; }
        atomicAdd(&stats[co], ts);
        atomicAdd(&stats[64 + co], t2);
    }
}

// ---------------- BN + ReLU, in place on d_out ----------------
__global__ __launch_bounds__(256) void bn_kernel(float* __restrict__ y,
                                                 const float* __restrict__ stats,
                                                 const float* __restrict__ gamma,
                                                 const float* __restrict__ beta) {
    size_t base = (size_t)blockIdx.x * 1024;
    int co = (int)((base >> 14) & 63);
    const float inv_n = 1.f / 65536.f;
    float mean = stats[co] * inv_n;
    float var  = stats[64 + co] * inv_n - mean * mean;
    float sc = gamma[co] * rsqrtf(var + EPSV);
    float sh = beta[co] - mean * sc;
    float4* p = (float4*)(y + base);
    float4 v = p[threadIdx.x];
    v.x = fmaxf(fmaf(v.x, sc, sh), 0.f);
    v.y = fmaxf(fmaf(v.y, sc, sh), 0.f);
    v.z = fmaxf(fmaf(v.z, sc, sh), 0.f);
    v.w = fmaxf(fmaf(v.w, sc, sh), 0.f);
    p[threadIdx.x] = v;
}

extern "C" void kernel_launch(void* const* d_in, const int* in_sizes, int n_in,
                              void* d_out, int out_size, void* d_ws, size_t ws_size,
                              hipStream_t stream) {
    const float* x     = (const float*)d_in[0];
    const float* w_off = (const float*)d_in[1];
    const float* b_off = (const float*)d_in[2];
    const float* wmat  = (const float*)d_in[3];
    const float* bvec  = (const float*)d_in[4];
    const float* gamma = (const float*)d_in[5];
    const float* beta  = (const float*)d_in[6];
    float* out = (float*)d_out;

    char* ws = (char*)d_ws;
    float* stats          = (float*)ws;                   // 512 B
    unsigned short* w_bf  = (unsigned short*)(ws + 1024); // 73728 B
    unsigned short* woA   = (unsigned short*)(ws + 74752);// 36864 B
    float* off            = (float*)(ws + 139264);        // 7077888 B

    hipMemsetAsync(stats, 0, 512, stream);
    prep_kernel<<<144, 256, 0, stream>>>(wmat, w_off, w_bf, woA);
    off_conv_kernel<<<1024, 256, 0, stream>>>(x, woA, off);
    deform_kernel<<<1024, 256, 0, stream>>>(x, w_bf, off, b_off, bvec, out);
    stats_kernel<<<dim3(CHO, NB), 256, 0, stream>>>(out, stats);
    bn_kernel<<<4096, 256, 0, stream>>>(out, stats, gamma, beta);
}